// Round 19
// baseline (181.341 us; speedup 1.0000x reference)
//
#include <hip/hip_runtime.h>
#include <hip/hip_bf16.h>

#define EMB 1024
#define NEXP 8
#define NH 1024
#define N_GU 2048
#define TOPK 2

#define BK 64
#define KTILES 16      // 1024 / 64
#define BN 128

// gate_up: BM=128 (measured best)
#define BMG 128
#define MAXTG 72
#define GRID_GU (MAXTG * 16)

// down: BM=64 (measured best)
#define BMD 64
#define MAXTD 160
#define GRID_DN (MAXTD * 8)

typedef __attribute__((ext_vector_type(4))) float f32x4;
typedef __attribute__((ext_vector_type(8))) short s16x8;
typedef __attribute__((ext_vector_type(4))) short s16x4;

typedef __attribute__((address_space(3))) unsigned int lds_u32;
typedef __attribute__((address_space(1))) const unsigned int glb_u32;

__device__ __forceinline__ void gl_lds16(const void* g, void* l) {
  __builtin_amdgcn_global_load_lds((glb_u32*)g, (lds_u32*)l, 16, 0, 0);
}

__device__ __forceinline__ unsigned short f2bf(float f) {
  union { float f; unsigned int u; } a; a.f = f;
  unsigned int u = a.u;
  unsigned int r = (u + 0x7FFFu + ((u >> 16) & 1u)) >> 16;
  return (unsigned short)r;
}

__device__ __forceinline__ float b2f(unsigned short h) {
  union { unsigned int u; float f; } a;
  a.u = ((unsigned int)h) << 16;
  return a.f;
}

__device__ __forceinline__ s16x8 pack8(float4 a, float4 b) {
  s16x8 p;
  p[0] = (short)f2bf(a.x); p[1] = (short)f2bf(a.y);
  p[2] = (short)f2bf(a.z); p[3] = (short)f2bf(a.w);
  p[4] = (short)f2bf(b.x); p[5] = (short)f2bf(b.y);
  p[6] = (short)f2bf(b.z); p[7] = (short)f2bf(b.w);
  return p;
}

// bijective chunked XCD swizzle (m204)
__device__ __forceinline__ int xcd_swz(int bid, int nwg) {
  int q = nwg >> 3, r = nwg & 7;
  int xcd = bid & 7, pos = bid >> 3;
  int base = (xcd < r) ? xcd * (q + 1) : r * (q + 1) + (xcd - r) * q;
  return base + pos;
}

// ---------------- dispatch 1: router + x fp32->bf16 ----------------
__global__ void router_convx(const float* __restrict__ x, unsigned short* __restrict__ xb, int n4x,
                             const float* __restrict__ rw, const float* __restrict__ rb, int T,
                             int* __restrict__ tokE, float* __restrict__ tokW) {
  int nr = T / 4;
  if ((int)blockIdx.x < nr) {
    int gwid = blockIdx.x * 4 + (threadIdx.x >> 6);
    int lane = threadIdx.x & 63;
    if (gwid >= T) return;
    const float* h = x + (size_t)gwid * EMB;
    float hreg[16];
    #pragma unroll
    for (int i = 0; i < 16; ++i) hreg[i] = h[lane + 64 * i];
    float sc[NEXP];
    #pragma unroll
    for (int e = 0; e < NEXP; ++e) {
      const float* w = rw + e * EMB;
      float s = 0.f;
      #pragma unroll
      for (int i = 0; i < 16; ++i) s += hreg[i] * w[lane + 64 * i];
      #pragma unroll
      for (int off = 32; off > 0; off >>= 1) s += __shfl_xor(s, off);
      sc[e] = s + rb[e];
    }
    if (lane == 0) {
      int e0 = 0; float v0 = sc[0];
      #pragma unroll
      for (int e = 1; e < NEXP; ++e) if (sc[e] > v0) { v0 = sc[e]; e0 = e; }
      int e1 = -1; float v1 = -3.0e38f;
      #pragma unroll
      for (int e = 0; e < NEXP; ++e) { if (e == e0) continue; if (sc[e] > v1) { v1 = sc[e]; e1 = e; } }
      float ex = __expf(v1 - v0);
      float w0 = 1.f / (1.f + ex);
      float w1 = ex / (1.f + ex);
      tokE[gwid * 2] = e0; tokE[gwid * 2 + 1] = e1;
      tokW[gwid * 2] = w0; tokW[gwid * 2 + 1] = w1;
    }
  } else {
    int base = (blockIdx.x - nr) * blockDim.x + threadIdx.x;
    int stride = (gridDim.x - nr) * blockDim.x;
    for (int i = base; i < n4x; i += stride) {
      float4 v = ((const float4*)x)[i];
      s16x4 o;
      o[0] = (short)f2bf(v.x);
      o[1] = (short)f2bf(v.y);
      o[2] = (short)f2bf(v.z);
      o[3] = (short)f2bf(v.w);
      ((s16x4*)xb)[i] = o;
    }
  }
}

// ---------------- dispatch 2: histogram + offsets + BOTH tile maps + scatter ----------------
__global__ void meta_scatter(const int* __restrict__ tokE, int A,
                             int* __restrict__ tmG, int* __restrict__ tmD,
                             int* __restrict__ rows, int* __restrict__ apos) {
  __shared__ int hist[NEXP];
  __shared__ int offs[NEXP];
  __shared__ int fill[NEXP];
  int t = threadIdx.x;
  if (t < NEXP) { hist[t] = 0; fill[t] = 0; }
  __syncthreads();
  for (int i = t; i < A; i += blockDim.x) atomicAdd(&hist[tokE[i]], 1);
  __syncthreads();
  if (t == 0) {
    int off = 0, ntg = 0, ntd = 0;
    for (int e = 0; e < NEXP; ++e) {
      offs[e] = off;
      int c = hist[e];
      int ng = (c + BMG - 1) / BMG;
      for (int k = 0; k < ng; ++k) {
        tmG[1 + ntg * 3 + 0] = e;
        tmG[1 + ntg * 3 + 1] = off + k * BMG;
        tmG[1 + ntg * 3 + 2] = off + c;
        ntg++;
      }
      int nd = (c + BMD - 1) / BMD;
      for (int k = 0; k < nd; ++k) {
        tmD[1 + ntd * 3 + 0] = e;
        tmD[1 + ntd * 3 + 1] = off + k * BMD;
        tmD[1 + ntd * 3 + 2] = off + c;
        ntd++;
      }
      off += c;
    }
    tmG[0] = ntg;
    tmD[0] = ntd;
  }
  __syncthreads();
  for (int i = t; i < A; i += blockDim.x) {
    int e = tokE[i];
    int p = offs[e] + atomicAdd(&fill[e], 1);
    rows[p] = i >> 1;
    apos[i] = p;
  }
}

// ---------------- grouped GEMM 1 (128x128): A=xb(bf16,gl_lds), B=guw fp32 reg-staged+cvt ----------------
// Eliminates the separate guw conversion pass (15 us of serial BW). Same 2-phase loop,
// same read-side swizzle; B staged global->reg->cvt->swizzled ds_write_b128 (T2 recipe).
__global__ __launch_bounds__(256, 4) void gemm_gate_up(
    const unsigned short* __restrict__ xb,
    const float* __restrict__ guw,
    const float* __restrict__ gu_bias,
    const int* __restrict__ rows,
    const int* __restrict__ tilemeta,
    unsigned short* __restrict__ hact) {
  __shared__ __align__(16) short As[BMG * BK];
  __shared__ __align__(16) short Bs[BN * BK];
  int wg = xcd_swz(blockIdx.x, GRID_GU);
  int tileid = wg >> 4;          // n = wg & 15 fast axis
  int n0 = (wg & 15) * BN;
  int nt = tilemeta[0];
  if (tileid >= nt) return;
  int e    = tilemeta[1 + tileid * 3 + 0];
  int m0   = tilemeta[1 + tileid * 3 + 1];
  int mEnd = tilemeta[1 + tileid * 3 + 2];

  int t = threadIdx.x;
  int lane = t & 63;
  int wid = t >> 6;
  int wr = wid >> 1, wc = wid & 1;

  int srow = lane >> 3;            // 0..7
  int nchunk = lane & 7;           // natural chunk for global fp32 read
  int scolA = ((nchunk ^ (srow & 7)) * 8);   // pre-swizzled source col for A's gl_lds
  const unsigned short* ga[4];
  const float* gbf[4];
  int dstA[4], dstB[4];
  #pragma unroll
  for (int q = 0; q < 4; ++q) {
    int rt = wid * 32 + q * 8 + srow;
    int ai = m0 + rt; if (ai >= mEnd) ai = mEnd - 1;
    ga[q] = xb + (size_t)rows[ai] * EMB + scolA;
    dstA[q] = (wid * 32 + q * 8) * BK;                     // wave-uniform (gl_lds)
    gbf[q] = guw + ((size_t)e * N_GU + n0 + rt) * EMB + nchunk * 8;
    dstB[q] = rt * BK + ((nchunk ^ (srow & 7)) * 8);       // per-lane swizzled (ds_write)
  }

  int fr = lane & 15;
  int q8 = (lane >> 4) * 8;
  int rsw = (fr & 7) << 3;

  f32x4 acc[4][4];
  #pragma unroll
  for (int i = 0; i < 4; ++i)
    #pragma unroll
    for (int j = 0; j < 4; ++j) acc[i][j] = (f32x4){0.f, 0.f, 0.f, 0.f};

  for (int tk = 0; tk < KTILES; ++tk) {
    int k0 = tk * BK;
    __syncthreads();
    // A: async gl_lds (bf16)
    #pragma unroll
    for (int q = 0; q < 4; ++q) gl_lds16(ga[q] + k0, &As[dstA[q]]);
    // B: fp32 loads first (max overlap), then cvt + swizzled ds_write
    float4 bl[4][2];
    #pragma unroll
    for (int q = 0; q < 4; ++q) {
      const float4* p = (const float4*)(gbf[q] + k0);
      bl[q][0] = p[0];
      bl[q][1] = p[1];
    }
    #pragma unroll
    for (int q = 0; q < 4; ++q)
      *(s16x8*)(&Bs[dstB[q]]) = pack8(bl[q][0], bl[q][1]);
    __syncthreads();
    #pragma unroll
    for (int kk = 0; kk < BK; kk += 32) {
      s16x8 a[4], b[4];
      #pragma unroll
      for (int i = 0; i < 4; ++i)
        a[i] = *(const s16x8*)(&As[(wr * 64 + i * 16 + fr) * BK + ((kk + q8) ^ rsw)]);
      #pragma unroll
      for (int j = 0; j < 4; ++j)
        b[j] = *(const s16x8*)(&Bs[(wc * 64 + j * 16 + fr) * BK + ((kk + q8) ^ rsw)]);
      #pragma unroll
      for (int i = 0; i < 4; ++i)
        #pragma unroll
        for (int j = 0; j < 4; ++j)
          acc[i][j] = __builtin_amdgcn_mfma_f32_16x16x32_bf16(a[i], b[j], acc[i][j], 0, 0, 0);
    }
  }

  const float* bias_e = gu_bias + (size_t)e * N_GU;
  int rbase = m0 + wr * 64 + ((lane >> 4) * 4);
  #pragma unroll
  for (int i = 0; i < 4; ++i) {
    #pragma unroll
    for (int j = 0; j < 4; ++j) {
      int n = n0 + wc * 64 + j * 16 + fr;
      float v[4], o[4];
      #pragma unroll
      for (int r = 0; r < 4; ++r) v[r] = acc[i][j][r] + bias_e[n];
      #pragma unroll
      for (int r = 0; r < 4; ++r) o[r] = __shfl_xor(v[r], 1);
      if ((lane & 1) == 0) {
        int outc = n >> 1;
        #pragma unroll
        for (int r = 0; r < 4; ++r) {
          int pos = rbase + i * 16 + r;
          if (pos < mEnd) {
            float g = v[r], u = o[r];
            float gc = fminf(fmaxf(g, -7.f), 7.f);
            float uc = fminf(fmaxf(u, -7.f), 7.f);
            float sig = 1.f / (1.f + __expf(-1.702f * g));
            float act = gc * sig * (uc + 1.f);
            hact[(size_t)pos * NH + outc] = f2bf(act);
          }
        }
      }
    }
  }
}

// ---------------- grouped GEMM 2 (64x128): A=hact(bf16,gl_lds), B=dw fp32 reg-staged+cvt ----------------
__global__ __launch_bounds__(256, 6) void gemm_down(
    const unsigned short* __restrict__ hact,
    const float* __restrict__ dw,
    const int* __restrict__ tilemeta,
    unsigned short* __restrict__ y) {
  __shared__ __align__(16) short As[BMD * BK];
  __shared__ __align__(16) short Bs[BN * BK];
  int wg = xcd_swz(blockIdx.x, gridDim.x);
  int tileid = wg >> 3;          // n = wg & 7 fast axis
  int n0 = (wg & 7) * BN;
  int nt = tilemeta[0];
  if (tileid >= nt) return;
  int e    = tilemeta[1 + tileid * 3 + 0];
  int m0   = tilemeta[1 + tileid * 3 + 1];
  int mEnd = tilemeta[1 + tileid * 3 + 2];

  int t = threadIdx.x;
  int lane = t & 63;
  int wid = t >> 6;
  int wr = wid >> 1, wc = wid & 1;

  int srow = lane >> 3;
  int nchunk = lane & 7;
  int scolA = ((nchunk ^ (srow & 7)) * 8);
  const unsigned short* ga[2];
  const float* gbf[4];
  int dstA[2], dstB[4];
  #pragma unroll
  for (int q = 0; q < 2; ++q) {
    int rt = q * 32 + wid * 8 + srow;
    int ai = m0 + rt; if (ai >= mEnd) ai = mEnd - 1;
    ga[q] = hact + (size_t)ai * NH + scolA;
    dstA[q] = (q * 32 + wid * 8) * BK;
  }
  #pragma unroll
  for (int q = 0; q < 4; ++q) {
    int rt = q * 32 + wid * 8 + srow;
    gbf[q] = dw + ((size_t)e * EMB + n0 + rt) * NH + nchunk * 8;
    dstB[q] = rt * BK + ((nchunk ^ (srow & 7)) * 8);
  }

  int fr = lane & 15;
  int q8 = (lane >> 4) * 8;
  int rsw = (fr & 7) << 3;

  f32x4 acc[2][4];
  #pragma unroll
  for (int i = 0; i < 2; ++i)
    #pragma unroll
    for (int j = 0; j < 4; ++j) acc[i][j] = (f32x4){0.f, 0.f, 0.f, 0.f};

  for (int tk = 0; tk < KTILES; ++tk) {
    int k0 = tk * BK;
    __syncthreads();
    #pragma unroll
    for (int q = 0; q < 2; ++q) gl_lds16(ga[q] + k0, &As[dstA[q]]);
    float4 bl[4][2];
    #pragma unroll
    for (int q = 0; q < 4; ++q) {
      const float4* p = (const float4*)(gbf[q] + k0);
      bl[q][0] = p[0];
      bl[q][1] = p[1];
    }
    #pragma unroll
    for (int q = 0; q < 4; ++q)
      *(s16x8*)(&Bs[dstB[q]]) = pack8(bl[q][0], bl[q][1]);
    __syncthreads();
    #pragma unroll
    for (int kk = 0; kk < BK; kk += 32) {
      s16x8 a[2], b[4];
      #pragma unroll
      for (int i = 0; i < 2; ++i)
        a[i] = *(const s16x8*)(&As[(wr * 32 + i * 16 + fr) * BK + ((kk + q8) ^ rsw)]);
      #pragma unroll
      for (int j = 0; j < 4; ++j)
        b[j] = *(const s16x8*)(&Bs[(wc * 64 + j * 16 + fr) * BK + ((kk + q8) ^ rsw)]);
      #pragma unroll
      for (int i = 0; i < 2; ++i)
        #pragma unroll
        for (int j = 0; j < 4; ++j)
          acc[i][j] = __builtin_amdgcn_mfma_f32_16x16x32_bf16(a[i], b[j], acc[i][j], 0, 0, 0);
    }
  }

  int rbase = m0 + wr * 32 + ((lane >> 4) * 4);
  #pragma unroll
  for (int i = 0; i < 2; ++i) {
    #pragma unroll
    for (int j = 0; j < 4; ++j) {
      int n = n0 + wc * 64 + j * 16 + fr;
      #pragma unroll
      for (int r = 0; r < 4; ++r) {
        int pos = rbase + i * 16 + r;
        if (pos < mEnd) y[(size_t)pos * EMB + n] = f2bf(acc[i][j][r]);
      }
    }
  }
}

// ---------------- final combine (bf16 y) ----------------
__global__ void combine_out(const unsigned short* __restrict__ y, const float* __restrict__ down_b,
                            const int* __restrict__ tokE, const float* __restrict__ tokW,
                            const int* __restrict__ apos, float* __restrict__ out, int T) {
  int i = blockIdx.x * blockDim.x + threadIdx.x;
  int tot = T * (EMB / 4);
  if (i >= tot) return;
  int tok = i >> 8;
  int c = i & 255;
  int e0 = tokE[tok * 2], e1 = tokE[tok * 2 + 1];
  float w0 = tokW[tok * 2], w1 = tokW[tok * 2 + 1];
  int p0 = apos[tok * 2], p1 = apos[tok * 2 + 1];
  s16x4 v0 = ((const s16x4*)(y + (size_t)p0 * EMB))[c];
  s16x4 v1 = ((const s16x4*)(y + (size_t)p1 * EMB))[c];
  float4 b0 = ((const float4*)(down_b + (size_t)e0 * EMB))[c];
  float4 b1 = ((const float4*)(down_b + (size_t)e1 * EMB))[c];
  float4 o;
  o.x = w0 * (b2f((unsigned short)v0[0]) + b0.x) + w1 * (b2f((unsigned short)v1[0]) + b1.x);
  o.y = w0 * (b2f((unsigned short)v0[1]) + b0.y) + w1 * (b2f((unsigned short)v1[1]) + b1.y);
  o.z = w0 * (b2f((unsigned short)v0[2]) + b0.z) + w1 * (b2f((unsigned short)v1[2]) + b1.z);
  o.w = w0 * (b2f((unsigned short)v0[3]) + b0.w) + w1 * (b2f((unsigned short)v1[3]) + b1.w);
  ((float4*)out)[i] = o;
}

extern "C" void kernel_launch(void* const* d_in, const int* in_sizes, int n_in,
                              void* d_out, int out_size, void* d_ws, size_t ws_size,
                              hipStream_t stream) {
  const float* x   = (const float*)d_in[0];
  const float* rw  = (const float*)d_in[1];
  const float* rb  = (const float*)d_in[2];
  const float* guw = (const float*)d_in[3];
  const float* gub = (const float*)d_in[4];
  const float* dw  = (const float*)d_in[5];
  const float* db  = (const float*)d_in[6];
  float* out = (float*)d_out;

  int T = in_sizes[0] / EMB;   // 4096
  int A = T * TOPK;            // 8192

  char* ws = (char*)d_ws;
  size_t off = 0;
  auto alloc = [&](size_t bytes) -> void* {
    void* p = ws + off;
    off = (off + bytes + 255) & ~((size_t)255);
    return p;
  };
  unsigned short* xb   = (unsigned short*)alloc((size_t)T * EMB * 2);
  unsigned short* hact = (unsigned short*)alloc((size_t)A * NH * 2);
  unsigned short* y    = (unsigned short*)alloc((size_t)A * EMB * 2);
  int*   tokE    = (int*)alloc((size_t)A * 4);
  float* tokW    = (float*)alloc((size_t)A * 4);
  int*   apos    = (int*)alloc((size_t)A * 4);
  int*   rowsArr = (int*)alloc((size_t)A * 4);
  int*   tmG     = (int*)alloc((1 + MAXTG * 3) * 4);
  int*   tmD     = (int*)alloc((1 + MAXTD * 3) * 4);

  int n4x = T * EMB / 4;

  router_convx<<<T / 4 + 1024, 256, 0, stream>>>(x, xb, n4x, rw, rb, T, tokE, tokW);
  meta_scatter<<<1, 1024, 0, stream>>>(tokE, A, tmG, tmD, rowsArr, apos);

  gemm_gate_up<<<GRID_GU, 256, 0, stream>>>(xb, guw, gub, rowsArr, tmG, hact);
  gemm_down<<<GRID_DN, 256, 0, stream>>>(hact, dw, tmD, y);

  combine_out<<<(T * EMB / 4 + 255) / 256, 256, 0, stream>>>(y, db, tokE, tokW, apos, out, T);
}

// Round 20
// 133.142 us; speedup vs baseline: 1.3620x; 1.3620x over previous
//
#include <hip/hip_runtime.h>
#include <hip/hip_bf16.h>

#define EMB 1024
#define NEXP 8
#define NH 1024
#define N_GU 2048
#define TOPK 2

#define BK 64
#define KTILES 16      // 1024 / 64
#define BN 128

// gate_up: BM=128 (measured best at its grid size)
#define BMG 128
#define MAXTG 72
#define GRID_GU (MAXTG * 16)
#define CONV_BLKS 256

// down: BM=64 (measured best at its grid size)
#define BMD 64
#define MAXTD 160
#define GRID_DN (MAXTD * 8)

typedef __attribute__((ext_vector_type(4))) float f32x4;
typedef __attribute__((ext_vector_type(8))) short s16x8;
typedef __attribute__((ext_vector_type(4))) short s16x4;

typedef __attribute__((address_space(3))) unsigned int lds_u32;
typedef __attribute__((address_space(1))) const unsigned int glb_u32;

__device__ __forceinline__ void gl_lds16(const void* g, void* l) {
  __builtin_amdgcn_global_load_lds((glb_u32*)g, (lds_u32*)l, 16, 0, 0);
}

__device__ __forceinline__ unsigned short f2bf(float f) {
  union { float f; unsigned int u; } a; a.f = f;
  unsigned int u = a.u;
  unsigned int r = (u + 0x7FFFu + ((u >> 16) & 1u)) >> 16;
  return (unsigned short)r;
}

__device__ __forceinline__ float b2f(unsigned short h) {
  union { unsigned int u; float f; } a;
  a.u = ((unsigned int)h) << 16;
  return a.f;
}

// bijective chunked XCD swizzle (m204)
__device__ __forceinline__ int xcd_swz(int bid, int nwg) {
  int q = nwg >> 3, r = nwg & 7;
  int xcd = bid & 7, pos = bid >> 3;
  int base = (xcd < r) ? xcd * (q + 1) : r * (q + 1) + (xcd - r) * q;
  return base + pos;
}

// ---------------- dispatch 1: router + x fp32->bf16 ----------------
__global__ void router_convx(const float* __restrict__ x, unsigned short* __restrict__ xb, int n4x,
                             const float* __restrict__ rw, const float* __restrict__ rb, int T,
                             int* __restrict__ tokE, float* __restrict__ tokW) {
  int nr = T / 4;
  if ((int)blockIdx.x < nr) {
    int gwid = blockIdx.x * 4 + (threadIdx.x >> 6);
    int lane = threadIdx.x & 63;
    if (gwid >= T) return;
    const float* h = x + (size_t)gwid * EMB;
    float hreg[16];
    #pragma unroll
    for (int i = 0; i < 16; ++i) hreg[i] = h[lane + 64 * i];
    float sc[NEXP];
    #pragma unroll
    for (int e = 0; e < NEXP; ++e) {
      const float* w = rw + e * EMB;
      float s = 0.f;
      #pragma unroll
      for (int i = 0; i < 16; ++i) s += hreg[i] * w[lane + 64 * i];
      #pragma unroll
      for (int off = 32; off > 0; off >>= 1) s += __shfl_xor(s, off);
      sc[e] = s + rb[e];
    }
    if (lane == 0) {
      int e0 = 0; float v0 = sc[0];
      #pragma unroll
      for (int e = 1; e < NEXP; ++e) if (sc[e] > v0) { v0 = sc[e]; e0 = e; }
      int e1 = -1; float v1 = -3.0e38f;
      #pragma unroll
      for (int e = 0; e < NEXP; ++e) { if (e == e0) continue; if (sc[e] > v1) { v1 = sc[e]; e1 = e; } }
      float ex = __expf(v1 - v0);
      float w0 = 1.f / (1.f + ex);
      float w1 = ex / (1.f + ex);
      tokE[gwid * 2] = e0; tokE[gwid * 2 + 1] = e1;
      tokW[gwid * 2] = w0; tokW[gwid * 2 + 1] = w1;
    }
  } else {
    int base = (blockIdx.x - nr) * blockDim.x + threadIdx.x;
    int stride = (gridDim.x - nr) * blockDim.x;
    for (int i = base; i < n4x; i += stride) {
      float4 v = ((const float4*)x)[i];
      s16x4 o;
      o[0] = (short)f2bf(v.x);
      o[1] = (short)f2bf(v.y);
      o[2] = (short)f2bf(v.z);
      o[3] = (short)f2bf(v.w);
      ((s16x4*)xb)[i] = o;
    }
  }
}

// ---------------- dispatch 2: meta/scatter (block 0) || guw fp32->bf16 (rest) ----------------
__global__ void meta_convw(const int* __restrict__ tokE, int A,
                           int* __restrict__ tmG, int* __restrict__ tmD,
                           int* __restrict__ rows, int* __restrict__ apos,
                           const float* __restrict__ guw, unsigned short* __restrict__ guwb, int n4g) {
  if (blockIdx.x > 0) {
    int base = (blockIdx.x - 1) * blockDim.x + threadIdx.x;
    int stride = (gridDim.x - 1) * blockDim.x;
    for (int i = base; i < n4g; i += stride) {
      float4 v = ((const float4*)guw)[i];
      s16x4 o;
      o[0] = (short)f2bf(v.x);
      o[1] = (short)f2bf(v.y);
      o[2] = (short)f2bf(v.z);
      o[3] = (short)f2bf(v.w);
      ((s16x4*)guwb)[i] = o;
    }
    return;
  }
  __shared__ int hist[NEXP];
  __shared__ int offs[NEXP];
  __shared__ int fill[NEXP];
  int t = threadIdx.x;
  if (t < NEXP) { hist[t] = 0; fill[t] = 0; }
  __syncthreads();
  for (int i = t; i < A; i += blockDim.x) atomicAdd(&hist[tokE[i]], 1);
  __syncthreads();
  if (t == 0) {
    int off = 0, ntg = 0, ntd = 0;
    for (int e = 0; e < NEXP; ++e) {
      offs[e] = off;
      int c = hist[e];
      int ng = (c + BMG - 1) / BMG;
      for (int k = 0; k < ng; ++k) {
        tmG[1 + ntg * 3 + 0] = e;
        tmG[1 + ntg * 3 + 1] = off + k * BMG;
        tmG[1 + ntg * 3 + 2] = off + c;
        ntg++;
      }
      int nd = (c + BMD - 1) / BMD;
      for (int k = 0; k < nd; ++k) {
        tmD[1 + ntd * 3 + 0] = e;
        tmD[1 + ntd * 3 + 1] = off + k * BMD;
        tmD[1 + ntd * 3 + 2] = off + c;
        ntd++;
      }
      off += c;
    }
    tmG[0] = ntg;
    tmD[0] = ntd;
  }
  __syncthreads();
  for (int i = t; i < A; i += blockDim.x) {
    int e = tokE[i];
    int p = offs[e] + atomicAdd(&fill[e], 1);
    rows[p] = i >> 1;
    apos[i] = p;
  }
}

// ---------------- grouped GEMM 1 (128x128): gathered x @ gate_up_w[e]^T, fused SwiGLU ----------------
// R12/R15-proven plain 2-phase loop, single-buffer 32KB LDS, 4 blocks/CU.
// CONV_BLKS leading converter-role blocks: dw fp32->bf16 co-resident with the GEMM (m114).
__global__ __launch_bounds__(256, 4) void gemm_gate_up(
    const unsigned short* __restrict__ xb,
    const unsigned short* __restrict__ gub,
    const float* __restrict__ gu_bias,
    const int* __restrict__ rows,
    const int* __restrict__ tilemeta,
    unsigned short* __restrict__ hact,
    const float* __restrict__ dw, unsigned short* __restrict__ dwb, int n4d) {
  __shared__ __align__(16) short As[BMG * BK];
  __shared__ __align__(16) short Bs[BN * BK];
  if ((int)blockIdx.x < CONV_BLKS) {
    int base = (int)blockIdx.x * blockDim.x + threadIdx.x;
    int stride = CONV_BLKS * blockDim.x;
    for (int i = base; i < n4d; i += stride) {
      float4 v = ((const float4*)dw)[i];
      s16x4 o;
      o[0] = (short)f2bf(v.x);
      o[1] = (short)f2bf(v.y);
      o[2] = (short)f2bf(v.z);
      o[3] = (short)f2bf(v.w);
      ((s16x4*)dwb)[i] = o;
    }
    return;
  }
  int wg = xcd_swz(blockIdx.x - CONV_BLKS, GRID_GU);
  int tileid = wg >> 4;          // n = wg & 15 fast axis
  int n0 = (wg & 15) * BN;
  int nt = tilemeta[0];
  if (tileid >= nt) return;
  int e    = tilemeta[1 + tileid * 3 + 0];
  int m0   = tilemeta[1 + tileid * 3 + 1];
  int mEnd = tilemeta[1 + tileid * 3 + 2];

  int t = threadIdx.x;
  int lane = t & 63;
  int wid = t >> 6;
  int wr = wid >> 1, wc = wid & 1;

  int srow = lane >> 3;
  int scol = (((lane & 7) ^ (srow & 7)) * 8);
  const unsigned short* ga[4];
  const unsigned short* gb[4];
  int dstoff[4];
  #pragma unroll
  for (int q = 0; q < 4; ++q) {
    int rt = wid * 32 + q * 8 + srow;
    int ai = m0 + rt; if (ai >= mEnd) ai = mEnd - 1;
    ga[q] = xb + (size_t)rows[ai] * EMB + scol;
    gb[q] = gub + ((size_t)e * N_GU + n0 + rt) * EMB + scol;
    dstoff[q] = (wid * 32 + q * 8) * BK;
  }

  int fr = lane & 15;
  int q8 = (lane >> 4) * 8;
  int rsw = (fr & 7) << 3;

  f32x4 acc[4][4];
  #pragma unroll
  for (int i = 0; i < 4; ++i)
    #pragma unroll
    for (int j = 0; j < 4; ++j) acc[i][j] = (f32x4){0.f, 0.f, 0.f, 0.f};

  for (int tk = 0; tk < KTILES; ++tk) {
    int k0 = tk * BK;
    __syncthreads();
    #pragma unroll
    for (int q = 0; q < 4; ++q) {
      gl_lds16(ga[q] + k0, &As[dstoff[q]]);
      gl_lds16(gb[q] + k0, &Bs[dstoff[q]]);
    }
    __syncthreads();
    #pragma unroll
    for (int kk = 0; kk < BK; kk += 32) {
      s16x8 a[4], b[4];
      #pragma unroll
      for (int i = 0; i < 4; ++i)
        a[i] = *(const s16x8*)(&As[(wr * 64 + i * 16 + fr) * BK + ((kk + q8) ^ rsw)]);
      #pragma unroll
      for (int j = 0; j < 4; ++j)
        b[j] = *(const s16x8*)(&Bs[(wc * 64 + j * 16 + fr) * BK + ((kk + q8) ^ rsw)]);
      #pragma unroll
      for (int i = 0; i < 4; ++i)
        #pragma unroll
        for (int j = 0; j < 4; ++j)
          acc[i][j] = __builtin_amdgcn_mfma_f32_16x16x32_bf16(a[i], b[j], acc[i][j], 0, 0, 0);
    }
  }

  const float* bias_e = gu_bias + (size_t)e * N_GU;
  int rbase = m0 + wr * 64 + ((lane >> 4) * 4);
  #pragma unroll
  for (int i = 0; i < 4; ++i) {
    #pragma unroll
    for (int j = 0; j < 4; ++j) {
      int n = n0 + wc * 64 + j * 16 + fr;
      float v[4], o[4];
      #pragma unroll
      for (int r = 0; r < 4; ++r) v[r] = acc[i][j][r] + bias_e[n];
      #pragma unroll
      for (int r = 0; r < 4; ++r) o[r] = __shfl_xor(v[r], 1);
      if ((lane & 1) == 0) {
        int outc = n >> 1;
        #pragma unroll
        for (int r = 0; r < 4; ++r) {
          int pos = rbase + i * 16 + r;
          if (pos < mEnd) {
            float g = v[r], u = o[r];
            float gc = fminf(fmaxf(g, -7.f), 7.f);
            float uc = fminf(fmaxf(u, -7.f), 7.f);
            float sig = 1.f / (1.f + __expf(-1.702f * g));
            float act = gc * sig * (uc + 1.f);
            hact[(size_t)pos * NH + outc] = f2bf(act);
          }
        }
      }
    }
  }
}

// ---------------- grouped GEMM 2 (64x128): hact @ down_w[e]^T -> y (bf16) ----------------
__global__ __launch_bounds__(256, 6) void gemm_down(
    const unsigned short* __restrict__ hact,
    const unsigned short* __restrict__ dwb,
    const int* __restrict__ tilemeta,
    unsigned short* __restrict__ y) {
  __shared__ __align__(16) short As[BMD * BK];
  __shared__ __align__(16) short Bs[BN * BK];
  int wg = xcd_swz(blockIdx.x, gridDim.x);
  int tileid = wg >> 3;          // n = wg & 7 fast axis
  int n0 = (wg & 7) * BN;
  int nt = tilemeta[0];
  if (tileid >= nt) return;
  int e    = tilemeta[1 + tileid * 3 + 0];
  int m0   = tilemeta[1 + tileid * 3 + 1];
  int mEnd = tilemeta[1 + tileid * 3 + 2];

  int t = threadIdx.x;
  int lane = t & 63;
  int wid = t >> 6;
  int wr = wid >> 1, wc = wid & 1;

  int srow = lane >> 3;
  int scol = (((lane & 7) ^ (srow & 7)) * 8);
  const unsigned short* ga[2];
  const unsigned short* gb[4];
  int dstA[2], dstB[4];
  #pragma unroll
  for (int q = 0; q < 2; ++q) {
    int rt = q * 32 + wid * 8 + srow;
    int ai = m0 + rt; if (ai >= mEnd) ai = mEnd - 1;
    ga[q] = hact + (size_t)ai * NH + scol;
    dstA[q] = (q * 32 + wid * 8) * BK;
  }
  #pragma unroll
  for (int q = 0; q < 4; ++q) {
    int rt = q * 32 + wid * 8 + srow;
    gb[q] = dwb + ((size_t)e * EMB + n0 + rt) * NH + scol;
    dstB[q] = (q * 32 + wid * 8) * BK;
  }

  int fr = lane & 15;
  int q8 = (lane >> 4) * 8;
  int rsw = (fr & 7) << 3;

  f32x4 acc[2][4];
  #pragma unroll
  for (int i = 0; i < 2; ++i)
    #pragma unroll
    for (int j = 0; j < 4; ++j) acc[i][j] = (f32x4){0.f, 0.f, 0.f, 0.f};

  for (int tk = 0; tk < KTILES; ++tk) {
    int k0 = tk * BK;
    __syncthreads();
    #pragma unroll
    for (int q = 0; q < 2; ++q) gl_lds16(ga[q] + k0, &As[dstA[q]]);
    #pragma unroll
    for (int q = 0; q < 4; ++q) gl_lds16(gb[q] + k0, &Bs[dstB[q]]);
    __syncthreads();
    #pragma unroll
    for (int kk = 0; kk < BK; kk += 32) {
      s16x8 a[2], b[4];
      #pragma unroll
      for (int i = 0; i < 2; ++i)
        a[i] = *(const s16x8*)(&As[(wr * 32 + i * 16 + fr) * BK + ((kk + q8) ^ rsw)]);
      #pragma unroll
      for (int j = 0; j < 4; ++j)
        b[j] = *(const s16x8*)(&Bs[(wc * 64 + j * 16 + fr) * BK + ((kk + q8) ^ rsw)]);
      #pragma unroll
      for (int i = 0; i < 2; ++i)
        #pragma unroll
        for (int j = 0; j < 4; ++j)
          acc[i][j] = __builtin_amdgcn_mfma_f32_16x16x32_bf16(a[i], b[j], acc[i][j], 0, 0, 0);
    }
  }

  int rbase = m0 + wr * 32 + ((lane >> 4) * 4);
  #pragma unroll
  for (int i = 0; i < 2; ++i) {
    #pragma unroll
    for (int j = 0; j < 4; ++j) {
      int n = n0 + wc * 64 + j * 16 + fr;
      #pragma unroll
      for (int r = 0; r < 4; ++r) {
        int pos = rbase + i * 16 + r;
        if (pos < mEnd) y[(size_t)pos * EMB + n] = f2bf(acc[i][j][r]);
      }
    }
  }
}

// ---------------- final combine (bf16 y) ----------------
__global__ void combine_out(const unsigned short* __restrict__ y, const float* __restrict__ down_b,
                            const int* __restrict__ tokE, const float* __restrict__ tokW,
                            const int* __restrict__ apos, float* __restrict__ out, int T) {
  int i = blockIdx.x * blockDim.x + threadIdx.x;
  int tot = T * (EMB / 4);
  if (i >= tot) return;
  int tok = i >> 8;
  int c = i & 255;
  int e0 = tokE[tok * 2], e1 = tokE[tok * 2 + 1];
  float w0 = tokW[tok * 2], w1 = tokW[tok * 2 + 1];
  int p0 = apos[tok * 2], p1 = apos[tok * 2 + 1];
  s16x4 v0 = ((const s16x4*)(y + (size_t)p0 * EMB))[c];
  s16x4 v1 = ((const s16x4*)(y + (size_t)p1 * EMB))[c];
  float4 b0 = ((const float4*)(down_b + (size_t)e0 * EMB))[c];
  float4 b1 = ((const float4*)(down_b + (size_t)e1 * EMB))[c];
  float4 o;
  o.x = w0 * (b2f((unsigned short)v0[0]) + b0.x) + w1 * (b2f((unsigned short)v1[0]) + b1.x);
  o.y = w0 * (b2f((unsigned short)v0[1]) + b0.y) + w1 * (b2f((unsigned short)v1[1]) + b1.y);
  o.z = w0 * (b2f((unsigned short)v0[2]) + b0.z) + w1 * (b2f((unsigned short)v1[2]) + b1.z);
  o.w = w0 * (b2f((unsigned short)v0[3]) + b0.w) + w1 * (b2f((unsigned short)v1[3]) + b1.w);
  ((float4*)out)[i] = o;
}

extern "C" void kernel_launch(void* const* d_in, const int* in_sizes, int n_in,
                              void* d_out, int out_size, void* d_ws, size_t ws_size,
                              hipStream_t stream) {
  const float* x   = (const float*)d_in[0];
  const float* rw  = (const float*)d_in[1];
  const float* rb  = (const float*)d_in[2];
  const float* guw = (const float*)d_in[3];
  const float* gub = (const float*)d_in[4];
  const float* dw  = (const float*)d_in[5];
  const float* db  = (const float*)d_in[6];
  float* out = (float*)d_out;

  int T = in_sizes[0] / EMB;   // 4096
  int A = T * TOPK;            // 8192

  char* ws = (char*)d_ws;
  size_t off = 0;
  auto alloc = [&](size_t bytes) -> void* {
    void* p = ws + off;
    off = (off + bytes + 255) & ~((size_t)255);
    return p;
  };
  unsigned short* xb   = (unsigned short*)alloc((size_t)T * EMB * 2);
  unsigned short* guwb = (unsigned short*)alloc((size_t)NEXP * N_GU * EMB * 2);
  unsigned short* dwb  = (unsigned short*)alloc((size_t)NEXP * EMB * NH * 2);
  unsigned short* hact = (unsigned short*)alloc((size_t)A * NH * 2);
  unsigned short* y    = (unsigned short*)alloc((size_t)A * EMB * 2);
  int*   tokE    = (int*)alloc((size_t)A * 4);
  float* tokW    = (float*)alloc((size_t)A * 4);
  int*   apos    = (int*)alloc((size_t)A * 4);
  int*   rowsArr = (int*)alloc((size_t)A * 4);
  int*   tmG     = (int*)alloc((1 + MAXTG * 3) * 4);
  int*   tmD     = (int*)alloc((1 + MAXTD * 3) * 4);

  int n4x = T * EMB / 4;
  int n4g = NEXP * N_GU * EMB / 4;
  int n4d = NEXP * EMB * NH / 4;

  router_convx<<<T / 4 + 1024, 256, 0, stream>>>(x, xb, n4x, rw, rb, T, tokE, tokW);
  meta_convw<<<1 + 2048, 1024, 0, stream>>>(tokE, A, tmG, tmD, rowsArr, apos, guw, guwb, n4g);

  gemm_gate_up<<<CONV_BLKS + GRID_GU, 256, 0, stream>>>(xb, guwb, gub, rowsArr, tmG, hact,
                                                        dw, dwb, n4d);
  gemm_down<<<GRID_DN, 256, 0, stream>>>(hact, dwb, tmD, y);

  combine_out<<<(T * EMB / 4 + 255) / 256, 256, 0, stream>>>(y, db, tokE, tokW, apos, out, T);
}